// Round 1
// baseline (424.199 us; speedup 1.0000x reference)
//
#include <hip/hip_runtime.h>
#include <math.h>

// SGRUCell: T=32, B=8, I=512, H=512. All f32.
// Decomposition: 256 blocks; block k owns state rows (b, i) for i in {2k,2k+1}, all b.
// F(t) kernel = [state update of step t-1] + [h/v row-compute of step t].
// Cross-block dependency per step is only h_t (16KB), carried via d_out outs region
// with kernel-boundary coherence.

__device__ __forceinline__ float wred(float v) {
#pragma unroll
  for (int o = 32; o > 0; o >>= 1) v += __shfl_xor(v, o, 64);
  return v;
}
__device__ __forceinline__ float sigm(float x) { return 1.f / (1.f + __expf(-x)); }

// one wave per row: row-norm scale s[o] = g[o]/||v[o]||  (rows are length 512)
__global__ void prenorm_kernel(const float* __restrict__ xv, const float* __restrict__ xg,
                               const float* __restrict__ hv, const float* __restrict__ hg,
                               float* __restrict__ scx, float* __restrict__ sch) {
  int r = blockIdx.x, L = threadIdx.x;
  const float* vrow; const float* g; float* o; int rr;
  if (r < 1536) { rr = r; vrow = xv + (size_t)r * 512; g = xg; o = scx; }
  else { rr = r - 1536; vrow = hv + (size_t)rr * 512; g = hg; o = sch; }
  float s = 0.f;
#pragma unroll
  for (int m = 0; m < 8; m++) { float v = vrow[m * 64 + L]; s = fmaf(v, v, s); }
  s = wred(s);
  if (L == 0) o[rr] = g[rr] / sqrtf(s);
}

__global__ __launch_bounds__(1024) void fstep_kernel(
    const float* __restrict__ x, int t,
    const float* __restrict__ hn_cur,   // h_t  (t==0: h0, else outs[t-1])
    const float* __restrict__ h_old,    // h_{t-1} (for te update of step t-1)
    const float* __restrict__ te_in, float* __restrict__ te_out,
    const float* __restrict__ dU_in, float* __restrict__ dU_out,
    const float* __restrict__ tE_in, float* __restrict__ tE_out,
    const float* __restrict__ v_in, float* __restrict__ v_out,
    float* __restrict__ hn_next, float* __restrict__ hn_next2,
    const float* __restrict__ scx, const float* __restrict__ sch,
    const float* __restrict__ x2h_v, const float* __restrict__ x2h_b,
    const float* __restrict__ h2h_v, const float* __restrict__ h2h_b,
    const float* __restrict__ alpha,
    const float* __restrict__ h2mod_w, const float* __restrict__ h2mod_b,
    const float* __restrict__ modU_w, const float* __restrict__ modU_b) {
  __shared__ float sh_hcur[4096];   // h_t  [b][c]
  __shared__ float sh_te[4096];     // te (old -> new in place)
  __shared__ float sh_w[5][2][512]; // Whz, Whdv, Wxz, Wxdv, alpha rows for i0, i0+1
  __shared__ float sh_gates[8][4];  // per-batch: tau_e, tau_E, tau_U, mU

  const int tid = threadIdx.x;
  const int w = tid >> 6, L = tid & 63;
  const int b = w & 7, ii = w >> 3;
  const int i0 = blockIdx.x * 2;
  const int i = i0 + ii;

  // ---- staging ----
#pragma unroll
  for (int k = 0; k < 4; k++) {
    int e = tid + k * 1024;
    sh_hcur[e] = hn_cur[e];
  }
  if (t > 0) {
#pragma unroll
    for (int k = 0; k < 4; k++) {
      int e = tid + k * 1024;
      sh_te[e] = te_in[e];
    }
  }
  {
    int ii2 = tid >> 9, c = tid & 511;
    int rz = i0 + ii2, rdv = 1024 + i0 + ii2;
    sh_w[0][ii2][c] = sch[rz] * h2h_v[(size_t)rz * 512 + c];
    sh_w[1][ii2][c] = sch[rdv] * h2h_v[(size_t)rdv * 512 + c];
    sh_w[2][ii2][c] = scx[rz] * x2h_v[(size_t)rz * 512 + c];
    sh_w[3][ii2][c] = scx[rdv] * x2h_v[(size_t)rdv * 512 + c];
    sh_w[4][ii2][c] = alpha[(size_t)rz * 512 + c];
  }
  __syncthreads();

  float dUreg[8];

  if (t > 0) {
    // ---- phase U: finish step s = t-1 ----
    // gates: mod = hn @ h2mod_w.T + h2mod_b  (hn = h_t), waves 0..7, one batch each
    if (w < 8) {
      float p0 = 0, p1 = 0, p2 = 0, p3 = 0;
      int base = w * 512;
#pragma unroll
      for (int m = 0; m < 8; m++) {
        int c = m * 64 + L;
        float hv_ = sh_hcur[base + c];
        p0 = fmaf(hv_, h2mod_w[c], p0);
        p1 = fmaf(hv_, h2mod_w[512 + c], p1);
        p2 = fmaf(hv_, h2mod_w[1024 + c], p2);
        p3 = fmaf(hv_, h2mod_w[1536 + c], p3);
      }
      p0 = wred(p0); p1 = wred(p1); p2 = wred(p2); p3 = wred(p3);
      if (L == 0) {
        sh_gates[w][0] = sigm(p0 + h2mod_b[0]);
        sh_gates[w][1] = sigm(p1 + h2mod_b[1]);
        sh_gates[w][2] = sigm(p2 + h2mod_b[2]);
        sh_gates[w][3] = fmaxf(p3 + h2mod_b[3], 0.f);
      }
    }
    __syncthreads();
    // te_n = te + tau_e*(h_old - te)   (h_old = h_{t-1}); in-place in LDS
#pragma unroll
    for (int k = 0; k < 4; k++) {
      int e = tid + k * 1024;
      float taue = sh_gates[e >> 9][0];
      sh_te[e] += taue * (h_old[e] - sh_te[e]);
    }
    __syncthreads();
    if (tid < 16) {  // designated canonical write of te_n slice
      int e = blockIdx.x * 16 + tid;
      te_out[e] = sh_te[e];
    }
    // tE / dU update for owned rows; up/lo recomputed from Wr, alpha
    float tauE = sh_gates[b][1], tauU = sh_gates[b][2], mU = sh_gates[b][3];
    float hn_i = sh_hcur[b * 512 + i];
    float te_i = sh_te[b * 512 + i];
    float schr = sch[512 + i];
    size_t row = ((size_t)(b * 512 + i)) * 512;
    size_t wrow = (size_t)i * 512;
    size_t rrow = (size_t)(512 + i) * 512;
#pragma unroll
    for (int m = 0; m < 8; m++) {
      int j = m * 64 + L;
      float dUo = dU_in[row + j];
      float tEo = tE_in[row + j];
      float te_j = sh_te[b * 512 + j];
      float hn_j = sh_hcur[b * 512 + j];
      float outer = hn_i * te_j - te_i * hn_j;
      float tEn = tEo + tauE * (outer - tEo);
      float a = fmaf(mU, modU_w[wrow + j], modU_b[wrow + j]);
      float sshr = (a > 0.5f) ? (a - 0.5f) : ((a < -0.5f) ? (a + 0.5f) : 0.f);
      float dUn = dUo + tauU * (sshr * tEn - dUo);
      float al = sh_w[4][ii][j];
      float wr = schr * h2h_v[rrow + j];
      float inv = 1.f / (al + 1e-5f);
      float up_ = fmaxf(1.f - wr, 0.f) * inv;
      float lo_ = -fmaxf(1.f + wr, 0.f) * inv;
      dUn = fminf(fmaxf(dUn, lo_), up_);
      tE_out[row + j] = tEn;
      dU_out[row + j] = dUn;
      dUreg[m] = dUn;
    }
  }

  if (t < 32) {
    // ---- phase R: step t row-compute: z, dv, v_n, hn ----
    int base = b * 512;
    size_t row = ((size_t)(base + i)) * 512;
    const float* xrow = x + (size_t)t * 4096 + base;
    float p1 = 0.f, p2 = 0.f;
#pragma unroll
    for (int m = 0; m < 8; m++) {
      int c = m * 64 + L;
      float hc = sh_hcur[base + c];
      float xc = xrow[c];
      float du = (t == 0) ? dU_in[row + c] : dUreg[m];
      p1 += sh_w[0][ii][c] * hc + sh_w[2][ii][c] * xc;
      p2 += sh_w[1][ii][c] * hc + sh_w[3][ii][c] * xc + sh_w[4][ii][c] * du * hc;
    }
    p1 = wred(p1); p2 = wred(p2);
    if (L == 0) {
      float z = sigm(p1 + x2h_b[i] + h2h_b[i]);
      float dv = p2 + x2h_b[1024 + i] + h2h_b[1024 + i];
      float vold = v_in[base + i];
      float vn = vold + z * (dv - vold);
      float hnv = fmaxf(vn, 0.f);
      v_out[base + i] = vn;
      hn_next[base + i] = hnv;
      if (hn_next2) hn_next2[base + i] = hnv;
    }
  }
}

extern "C" void kernel_launch(void* const* d_in, const int* in_sizes, int n_in,
                              void* d_out, int out_size, void* d_ws, size_t ws_size,
                              hipStream_t stream) {
  const float* x       = (const float*)d_in[0];
  const float* h0      = (const float*)d_in[1];
  const float* v0      = (const float*)d_in[2];
  const float* dU0     = (const float*)d_in[3];
  const float* te0     = (const float*)d_in[4];
  const float* tE0     = (const float*)d_in[5];
  const float* x2h_v   = (const float*)d_in[6];
  const float* x2h_g   = (const float*)d_in[7];
  const float* x2h_b   = (const float*)d_in[8];
  const float* h2h_v   = (const float*)d_in[9];
  const float* h2h_g   = (const float*)d_in[10];
  const float* h2h_b   = (const float*)d_in[11];
  const float* alpha   = (const float*)d_in[12];
  const float* h2mod_w = (const float*)d_in[13];
  const float* h2mod_b = (const float*)d_in[14];
  const float* modU_w  = (const float*)d_in[15];
  const float* modU_b  = (const float*)d_in[16];

  float* out = (float*)d_out;
  // output layout: v(4096) h(4096) dU(2097152) te(4096) tE(2097152) outs(131072)
  float* o_v    = out;
  float* o_h    = out + 4096;
  float* o_dU   = out + 8192;
  float* o_te   = out + 2105344;
  float* o_tE   = out + 2109440;
  float* o_outs = out + 4206592;

  float* wsf  = (float*)d_ws;
  float* scx  = wsf;         // 1536
  float* sch  = wsf + 1536;  // 1536
  float* ws_te = wsf + 3072; // 2*4096 double buffer

  prenorm_kernel<<<dim3(3072), dim3(64), 0, stream>>>(x2h_v, x2h_g, h2h_v, h2h_g, scx, sch);

  for (int t = 0; t <= 32; t++) {
    int s = t - 1;  // step finished by phase U
    const float* hn_cur = (t == 0) ? h0 : o_outs + (size_t)(t - 1) * 4096;
    const float* hold   = (t <= 1) ? h0 : o_outs + (size_t)(t - 2) * 4096;
    const float* te_in  = (t <= 1) ? te0 : ws_te + (size_t)((s + 1) & 1) * 4096;
    float* te_out       = (t == 0) ? ws_te : ((s == 31) ? o_te : ws_te + (size_t)(s & 1) * 4096);
    const float* dU_in  = (t <= 1) ? dU0 : o_dU;
    const float* tE_in  = (t <= 1) ? tE0 : o_tE;
    float* hn_next  = (t < 32) ? (o_outs + (size_t)t * 4096) : o_outs;  // unused at t==32
    float* hn_next2 = (t == 31) ? o_h : nullptr;
    const float* v_in = (t == 0) ? v0 : o_v;

    fstep_kernel<<<dim3(256), dim3(1024), 0, stream>>>(
        x, t, hn_cur, hold, te_in, te_out, dU_in, o_dU, tE_in, o_tE,
        v_in, o_v, hn_next, hn_next2, scx, sch,
        x2h_v, x2h_b, h2h_v, h2h_b, alpha, h2mod_w, h2mod_b, modU_w, modU_b);
  }
}